// Round 7
// baseline (136.319 us; speedup 1.0000x reference)
//
#include <hip/hip_runtime.h>
#include <hip/hip_bf16.h>

// Dims fixed by setup_inputs(): b=8, t=64, s=512, qu=vu=d=512.
#define B_  8
#define T_  64
#define S_  512
#define D_  512

#define QN (512 * 512)      // qproj elements (B*T x D)
#define KN (4096 * 512)     // kproj elements (B*S x D)

#define TLOG2E 2.8853900817779268f   // 2*log2(e)
#define LOG2E  1.4426950408889634f

typedef __attribute__((ext_vector_type(8))) short bf16x8;
typedef __attribute__((ext_vector_type(4))) float f32x4;

// RNE f32x2 -> packed bf16x2 via v_cvt_pk_bf16_f32 (1 inst; bit-identical to
// manual RNE used in R5/R6).
__device__ __forceinline__ unsigned int pk2(float a, float b) {
    float2 f; f.x = a; f.y = b;
    __hip_bfloat162 h = __float22bfloat162_rn(f);
    return *(unsigned int*)&h;
}

// ---------------------------------------------------------------------------
// bf16 MFMA projection GEMM with inline f32->bf16 packing (R6 structure,
// pk2 swapped to cvt_pk). Block = 64x64 tile, 4 waves, 2x2 of 16x16x32 mfma.
//   blocks [0,512):   kproj = value @ W2  (tm = (x&7)*8 + ((x>>3)&7), tn=x>>6)
//   blocks [512,576): qproj = query @ W1  (r=x-512: tm=r>>3, tn=r&7)
// Epilogue: *TLOG2E; q-GEMM adds (b1+b2) first.
// ---------------------------------------------------------------------------
__global__ __launch_bounds__(256) void mfma_gemm(
    const float* __restrict__ query, const float* __restrict__ value,
    const float* __restrict__ W1, const float* __restrict__ W2,
    const float* __restrict__ b1, const float* __restrict__ b2,
    float* __restrict__ qproj, float* __restrict__ kproj)
{
    __shared__ __align__(16) unsigned short Ab[64][40];
    __shared__ __align__(16) unsigned short Bs[64][40];

    const int x = blockIdx.x;
    const float *A, *W;
    float* C;
    int tm, tn;
    bool isq;
    if (x < 512) {
        tm = (x & 7) * 8 + ((x >> 3) & 7);
        tn = x >> 6;
        A = value; W = W2; C = kproj; isq = false;
    } else {
        int r = x - 512;
        tm = r >> 3; tn = r & 7;
        A = query; W = W1; C = qproj; isq = true;
    }

    const int tid  = threadIdx.x;
    const int lane = tid & 63;
    const int wid  = tid >> 6;
    const int wm = (wid & 1) * 32, wn = (wid >> 1) * 32;
    const int fm = lane & 15, fq = lane >> 4;

    f32x4 acc00 = {0.f, 0.f, 0.f, 0.f};
    f32x4 acc01 = acc00, acc10 = acc00, acc11 = acc00;

    const int ar = tid >> 2;
    const int ac = (tid & 3) * 8;
    const float* Ag = A + (size_t)(tm * 64 + ar) * 512 + ac;
    const int c0 = (tid & 15) * 4;
    const int kp = (tid >> 4) * 2;
    const float* Wg = W + (size_t)kp * 512 + tn * 64 + c0;

    float4 av0 = *(const float4*)(Ag);
    float4 av1 = *(const float4*)(Ag + 4);
    float4 wv0 = *(const float4*)(Wg);
    float4 wv1 = *(const float4*)(Wg + 512);

    for (int k0 = 0; k0 < 512; k0 += 32) {
        __syncthreads();
        {
            uint4 pa;
            pa.x = pk2(av0.x, av0.y); pa.y = pk2(av0.z, av0.w);
            pa.z = pk2(av1.x, av1.y); pa.w = pk2(av1.z, av1.w);
            *(uint4*)&Ab[ar][ac] = pa;
            *(unsigned int*)&Bs[c0 + 0][kp] = pk2(wv0.x, wv1.x);
            *(unsigned int*)&Bs[c0 + 1][kp] = pk2(wv0.y, wv1.y);
            *(unsigned int*)&Bs[c0 + 2][kp] = pk2(wv0.z, wv1.z);
            *(unsigned int*)&Bs[c0 + 3][kp] = pk2(wv0.w, wv1.w);
        }
        __syncthreads();
        const int kn = (k0 + 32) & 511;
        av0 = *(const float4*)(Ag + kn);
        av1 = *(const float4*)(Ag + kn + 4);
        wv0 = *(const float4*)(Wg + (size_t)kn * 512);
        wv1 = *(const float4*)(Wg + (size_t)kn * 512 + 512);

        bf16x8 a0  = *(const bf16x8*)&Ab[wm + fm][fq * 8];
        bf16x8 a1  = *(const bf16x8*)&Ab[wm + 16 + fm][fq * 8];
        bf16x8 b0  = *(const bf16x8*)&Bs[wn + fm][fq * 8];
        bf16x8 b1v = *(const bf16x8*)&Bs[wn + 16 + fm][fq * 8];
        acc00 = __builtin_amdgcn_mfma_f32_16x16x32_bf16(a0, b0,  acc00, 0, 0, 0);
        acc01 = __builtin_amdgcn_mfma_f32_16x16x32_bf16(a0, b1v, acc01, 0, 0, 0);
        acc10 = __builtin_amdgcn_mfma_f32_16x16x32_bf16(a1, b0,  acc10, 0, 0, 0);
        acc11 = __builtin_amdgcn_mfma_f32_16x16x32_bf16(a1, b1v, acc11, 0, 0, 0);
    }

    // C/D layout (m89-verified): col = lane&15, row = fq*4 + reg.
    const int n0 = tn * 64 + wn + fm;
    const int n1 = n0 + 16;
    float bias0 = 0.f, bias1 = 0.f;
    if (isq) {
        bias0 = b1[n0] + b2[n0];
        bias1 = b1[n1] + b2[n1];
    }
    const int m0 = tm * 64 + wm + fq * 4;
#pragma unroll
    for (int r = 0; r < 4; ++r) {
        C[(size_t)(m0 + r) * 512 + n0]      = (acc00[r] + bias0) * TLOG2E;
        C[(size_t)(m0 + r) * 512 + n1]      = (acc01[r] + bias1) * TLOG2E;
        C[(size_t)(m0 + 16 + r) * 512 + n0] = (acc10[r] + bias0) * TLOG2E;
        C[(size_t)(m0 + 16 + r) * 512 + n1] = (acc11[r] + bias1) * TLOG2E;
    }
}

// ---------------------------------------------------------------------------
// Fused scores + softmax + context. Grid 256 = (tp << 3) | b (b = XCD pin,
// batch b's kproj+value resident in XCD b's L2). Block = one t-PAIR, 512 thr.
//
// Phase 1 (scores): thread s streams its OWN k-row from global in 64 B
//   register chunks (no LDS tile, no barriers); q0/delta/scale are LDS
//   broadcasts (SoA). Exp-share: e1 = e0 * delta_d, delta_d = exp2(q1-q0)
//   precomputed -> 1.5 trans/element (201M device-wide, ~10 us floor).
//   Stored score = -2 * sum c*rcp(...) (csum dropped; softmax shift-inv).
// Phase 2 (softmax): scores live in registers (thread-per-s); 6-shfl wave
//   reduce + 8-wave LDS combine, packed float2 for the t-pair.
// Phase 3 (context): thread (g = s-quarter, v4): float4 value loads
//   (value[b] read exactly once per block = 256 MB total), both t's
//   accumulated; 4-partial LDS combine.
// ---------------------------------------------------------------------------
__global__ __launch_bounds__(512, 2) void fused_attn(
    const float* __restrict__ qproj, const float* __restrict__ kproj,
    const int*   __restrict__ mask,  const float* __restrict__ scale,
    const float* __restrict__ value,
    float* __restrict__ ctx, float* __restrict__ attn)
{
    const int blk = blockIdx.x;
    const int b  = blk & 7;
    const int tp = blk >> 3;          // 0..31
    const size_t row0 = (size_t)(b * T_ + tp * 2);

    __shared__ __align__(16) float q0A[512];
    __shared__ __align__(16) float dA[512];
    __shared__ __align__(16) float cA[512];
    __shared__ __align__(16) float2 wp2[512];
    __shared__ __align__(16) float4 part[2][4][128];
    __shared__ float2 red2[16];

    const int tid  = threadIdx.x;     // 0..511
    const int lane = tid & 63;
    const int wid  = tid >> 6;        // 0..7

    // ---- Phase 0: q0 / delta / scale into LDS (SoA) ----
    {
        float q0v = qproj[row0 * D_ + tid];
        float q1v = qproj[(row0 + 1) * D_ + tid];
        q0A[tid] = q0v;
        dA[tid]  = __builtin_amdgcn_exp2f(q1v - q0v);   // delta_d
        cA[tid]  = scale[tid];
    }
    __syncthreads();

    // ---- Phase 1: thread s = tid ----
    const int s = tid;
    const int m = mask[b * S_ + s];
    const float* kr = kproj + (size_t)(b * S_ + s) * D_;
    float p0 = 0.f, p1 = 0.f;

    float4 kf0 = ((const float4*)kr)[0];
    float4 kf1 = ((const float4*)kr)[1];
    float4 kf2 = ((const float4*)kr)[2];
    float4 kf3 = ((const float4*)kr)[3];

#define SC_STEP(K4, DD) do {                                                  \
        float4 q4 = *(const float4*)&q0A[DD];                                 \
        float4 dl = *(const float4*)&dA[DD];                                  \
        float4 c4 = *(const float4*)&cA[DD];                                  \
        float e, ra, rb;                                                      \
        e  = __builtin_amdgcn_exp2f(q4.x + (K4).x);                           \
        ra = __builtin_amdgcn_rcpf(e + 1.0f);                                 \
        rb = __builtin_amdgcn_rcpf(fmaf(e, dl.x, 1.0f));                      \
        p0 = fmaf(c4.x, ra, p0); p1 = fmaf(c4.x, rb, p1);                     \
        e  = __builtin_amdgcn_exp2f(q4.y + (K4).y);                           \
        ra = __builtin_amdgcn_rcpf(e + 1.0f);                                 \
        rb = __builtin_amdgcn_rcpf(fmaf(e, dl.y, 1.0f));                      \
        p0 = fmaf(c4.y, ra, p0); p1 = fmaf(c4.y, rb, p1);                     \
        e  = __builtin_amdgcn_exp2f(q4.z + (K4).z);                           \
        ra = __builtin_amdgcn_rcpf(e + 1.0f);                                 \
        rb = __builtin_amdgcn_rcpf(fmaf(e, dl.z, 1.0f));                      \
        p0 = fmaf(c4.z, ra, p0); p1 = fmaf(c4.z, rb, p1);                     \
        e  = __builtin_amdgcn_exp2f(q4.w + (K4).w);                           \
        ra = __builtin_amdgcn_rcpf(e + 1.0f);                                 \
        rb = __builtin_amdgcn_rcpf(fmaf(e, dl.w, 1.0f));                      \
        p0 = fmaf(c4.w, ra, p0); p1 = fmaf(c4.w, rb, p1);                     \
    } while (0)

    for (int c = 0; c < 32; ++c) {
        const int nx = ((c + 1) & 31) * 16;   // wrap prefetch (last redundant)
        float4 nf0 = ((const float4*)(kr + nx))[0];
        float4 nf1 = ((const float4*)(kr + nx))[1];
        float4 nf2 = ((const float4*)(kr + nx))[2];
        float4 nf3 = ((const float4*)(kr + nx))[3];
        const int d0 = c * 16;
        SC_STEP(kf0, d0);
        SC_STEP(kf1, d0 + 4);
        SC_STEP(kf2, d0 + 8);
        SC_STEP(kf3, d0 + 12);
        kf0 = nf0; kf1 = nf1; kf2 = nf2; kf3 = nf3;
    }
#undef SC_STEP

    float x0 = m ? (-2.0f * p0) : -1e9f;
    float x1 = m ? (-2.0f * p1) : -1e9f;

    // ---- Phase 2: softmax over 512 s (packed t-pair) ----
    float2 mx; mx.x = x0; mx.y = x1;
#pragma unroll
    for (int off = 32; off >= 1; off >>= 1) {
        mx.x = fmaxf(mx.x, __shfl_xor(mx.x, off));
        mx.y = fmaxf(mx.y, __shfl_xor(mx.y, off));
    }
    if (lane == 0) red2[wid] = mx;
    __syncthreads();
    float2 M = red2[0];
#pragma unroll
    for (int i = 1; i < 8; ++i) {
        M.x = fmaxf(M.x, red2[i].x);
        M.y = fmaxf(M.y, red2[i].y);
    }

    float e0 = __builtin_amdgcn_exp2f((x0 - M.x) * LOG2E);
    float e1 = __builtin_amdgcn_exp2f((x1 - M.y) * LOG2E);
    float2 sm; sm.x = e0; sm.y = e1;
#pragma unroll
    for (int off = 32; off >= 1; off >>= 1) {
        sm.x += __shfl_xor(sm.x, off);
        sm.y += __shfl_xor(sm.y, off);
    }
    if (lane == 0) red2[8 + wid] = sm;
    __syncthreads();
    float2 SS = red2[8];
#pragma unroll
    for (int i = 9; i < 16; ++i) {
        SS.x += red2[i].x;
        SS.y += red2[i].y;
    }
    const float inv0 = __builtin_amdgcn_rcpf(SS.x);
    const float inv1 = __builtin_amdgcn_rcpf(SS.y);
    const float w0 = e0 * inv0, w1 = e1 * inv1;

    float2 wpair; wpair.x = w0; wpair.y = w1;
    wp2[s] = wpair;
    attn[row0 * S_ + s]       = w0;
    attn[(row0 + 1) * S_ + s] = w1;
    __syncthreads();

    // ---- Phase 3: context ----
    const int g  = tid >> 7;          // s-quarter 0..3
    const int v4 = tid & 127;         // float4 slot 0..127
    const float* vb = value + ((size_t)(b * S_) + g * 128) * D_ + v4 * 4;
    float4 a0; a0.x = 0.f; a0.y = 0.f; a0.z = 0.f; a0.w = 0.f;
    float4 a1 = a0;
#pragma unroll 4
    for (int i = 0; i < 128; ++i) {
        float4 vv = *(const float4*)(vb + (size_t)i * D_);
        float2 w = wp2[g * 128 + i];
        a0.x = fmaf(w.x, vv.x, a0.x); a0.y = fmaf(w.x, vv.y, a0.y);
        a0.z = fmaf(w.x, vv.z, a0.z); a0.w = fmaf(w.x, vv.w, a0.w);
        a1.x = fmaf(w.y, vv.x, a1.x); a1.y = fmaf(w.y, vv.y, a1.y);
        a1.z = fmaf(w.y, vv.z, a1.z); a1.w = fmaf(w.y, vv.w, a1.w);
    }
    part[0][g][v4] = a0;
    part[1][g][v4] = a1;
    __syncthreads();
    if (tid < 256) {
        const int t = tid >> 7, v = tid & 127;
        float4 p0v = part[t][0][v], p1v = part[t][1][v];
        float4 p2v = part[t][2][v], p3v = part[t][3][v];
        float4 o;
        o.x = (p0v.x + p1v.x) + (p2v.x + p3v.x);
        o.y = (p0v.y + p1v.y) + (p2v.y + p3v.y);
        o.z = (p0v.z + p1v.z) + (p2v.z + p3v.z);
        o.w = (p0v.w + p1v.w) + (p2v.w + p3v.w);
        *(float4*)(ctx + (row0 + t) * D_ + v * 4) = o;
    }
}

extern "C" void kernel_launch(void* const* d_in, const int* in_sizes, int n_in,
                              void* d_out, int out_size, void* d_ws, size_t ws_size,
                              hipStream_t stream) {
    const float* query = (const float*)d_in[0];
    const float* value = (const float*)d_in[1];
    const int*   mask  = (const int*)  d_in[2];
    const float* W1w   = (const float*)d_in[3];
    const float* W1b   = (const float*)d_in[4];
    const float* W2w   = (const float*)d_in[5];
    const float* W2b   = (const float*)d_in[6];
    const float* scale = (const float*)d_in[7];

    float* ctx  = (float*)d_out;
    float* attn = (float*)d_out + (size_t)B_ * T_ * D_;

    float* qproj = (float*)d_ws;              // QN f32 (1 MB)
    float* kproj = qproj + (size_t)QN;        // KN f32 (8 MB)

    mfma_gemm<<<576, 256, 0, stream>>>(query, value, W1w, W2w, W1b, W2b,
                                       qproj, kproj);
    fused_attn<<<256, 512, 0, stream>>>(qproj, kproj, mask, scale, value,
                                        ctx, attn);
}

// Round 8
// 133.758 us; speedup vs baseline: 1.0191x; 1.0191x over previous
//
#include <hip/hip_runtime.h>
#include <hip/hip_bf16.h>

// Dims fixed by setup_inputs(): b=8, t=64, s=512, qu=vu=d=512.
#define B_  8
#define T_  64
#define S_  512
#define D_  512

#define QN (512 * 512)      // qproj elements (B*T x D)
#define KN (4096 * 512)     // kproj elements (B*S x D)

#define TLOG2E 2.8853900817779268f   // 2*log2(e)
#define LOG2E  1.4426950408889634f

typedef __attribute__((ext_vector_type(8))) short bf16x8;
typedef __attribute__((ext_vector_type(4))) float f32x4;

// RNE f32x2 -> packed bf16x2 via v_cvt_pk_bf16_f32.
__device__ __forceinline__ unsigned int pk2(float a, float b) {
    float2 f; f.x = a; f.y = b;
    __hip_bfloat162 h = __float22bfloat162_rn(f);
    return *(unsigned int*)&h;
}

// ---------------------------------------------------------------------------
// bf16 MFMA projection GEMM, inline f32->bf16 pack, DOUBLE-BUFFERED LDS:
// one barrier per K-iter (16 total, was 32), prefetch distance 2 iters.
// Block = 64x64 tile, 4 waves, 2x2 of 16x16x32 mfma.
//   blocks [0,512):   kproj = value @ W2  (tm = (x&7)*8 + ((x>>3)&7), tn=x>>6)
//   blocks [512,576): qproj = query @ W1  (r=x-512: tm=r>>3, tn=r&7)
// Epilogue: *TLOG2E; q-GEMM adds (b1+b2) first.
// ---------------------------------------------------------------------------
__global__ __launch_bounds__(256) void mfma_gemm(
    const float* __restrict__ query, const float* __restrict__ value,
    const float* __restrict__ W1, const float* __restrict__ W2,
    const float* __restrict__ b1, const float* __restrict__ b2,
    float* __restrict__ qproj, float* __restrict__ kproj)
{
    __shared__ __align__(16) unsigned short Ab[2][64][40];
    __shared__ __align__(16) unsigned short Bs[2][64][40];

    const int x = blockIdx.x;
    const float *A, *W;
    float* C;
    int tm, tn;
    bool isq;
    if (x < 512) {
        tm = (x & 7) * 8 + ((x >> 3) & 7);
        tn = x >> 6;
        A = value; W = W2; C = kproj; isq = false;
    } else {
        int r = x - 512;
        tm = r >> 3; tn = r & 7;
        A = query; W = W1; C = qproj; isq = true;
    }

    const int tid  = threadIdx.x;
    const int lane = tid & 63;
    const int wid  = tid >> 6;
    const int wm = (wid & 1) * 32, wn = (wid >> 1) * 32;
    const int fm = lane & 15, fq = lane >> 4;

    f32x4 acc00 = {0.f, 0.f, 0.f, 0.f};
    f32x4 acc01 = acc00, acc10 = acc00, acc11 = acc00;

    const int ar = tid >> 2;
    const int ac = (tid & 3) * 8;
    const float* Ag = A + (size_t)(tm * 64 + ar) * 512 + ac;
    const int c0 = (tid & 15) * 4;
    const int kp = (tid >> 4) * 2;
    const float* Wg = W + (size_t)kp * 512 + tn * 64 + c0;

    float4 av0, av1, wv0, wv1;

#define STAGE(BUF) do {                                                       \
        uint4 pa;                                                             \
        pa.x = pk2(av0.x, av0.y); pa.y = pk2(av0.z, av0.w);                   \
        pa.z = pk2(av1.x, av1.y); pa.w = pk2(av1.z, av1.w);                   \
        *(uint4*)&Ab[BUF][ar][ac] = pa;                                       \
        *(unsigned int*)&Bs[BUF][c0 + 0][kp] = pk2(wv0.x, wv1.x);             \
        *(unsigned int*)&Bs[BUF][c0 + 1][kp] = pk2(wv0.y, wv1.y);             \
        *(unsigned int*)&Bs[BUF][c0 + 2][kp] = pk2(wv0.z, wv1.z);             \
        *(unsigned int*)&Bs[BUF][c0 + 3][kp] = pk2(wv0.w, wv1.w);             \
    } while (0)

    // tile 0 -> buf0; tile 1 -> regs
    av0 = *(const float4*)(Ag);
    av1 = *(const float4*)(Ag + 4);
    wv0 = *(const float4*)(Wg);
    wv1 = *(const float4*)(Wg + 512);
    STAGE(0);
    av0 = *(const float4*)(Ag + 32);
    av1 = *(const float4*)(Ag + 36);
    wv0 = *(const float4*)(Wg + 32 * 512);
    wv1 = *(const float4*)(Wg + 33 * 512);
    __syncthreads();

#pragma unroll
    for (int i = 0; i < 16; ++i) {
        const int cur = i & 1, nxt = cur ^ 1;
        bf16x8 a0  = *(const bf16x8*)&Ab[cur][wm + fm][fq * 8];
        bf16x8 a1  = *(const bf16x8*)&Ab[cur][wm + 16 + fm][fq * 8];
        bf16x8 b0  = *(const bf16x8*)&Bs[cur][wn + fm][fq * 8];
        bf16x8 b1v = *(const bf16x8*)&Bs[cur][wn + 16 + fm][fq * 8];
        if (i < 15) {
            STAGE(nxt);                          // tile i+1 -> other buffer
            const int kn = ((i + 2) & 15) * 32;  // prefetch tile i+2 (wrap)
            av0 = *(const float4*)(Ag + kn);
            av1 = *(const float4*)(Ag + kn + 4);
            wv0 = *(const float4*)(Wg + (size_t)kn * 512);
            wv1 = *(const float4*)(Wg + (size_t)kn * 512 + 512);
        }
        acc00 = __builtin_amdgcn_mfma_f32_16x16x32_bf16(a0, b0,  acc00, 0, 0, 0);
        acc01 = __builtin_amdgcn_mfma_f32_16x16x32_bf16(a0, b1v, acc01, 0, 0, 0);
        acc10 = __builtin_amdgcn_mfma_f32_16x16x32_bf16(a1, b0,  acc10, 0, 0, 0);
        acc11 = __builtin_amdgcn_mfma_f32_16x16x32_bf16(a1, b1v, acc11, 0, 0, 0);
        __syncthreads();
    }
#undef STAGE

    // C/D layout (m89-verified): col = lane&15, row = fq*4 + reg.
    const int n0 = tn * 64 + wn + fm;
    const int n1 = n0 + 16;
    float bias0 = 0.f, bias1 = 0.f;
    if (isq) {
        bias0 = b1[n0] + b2[n0];
        bias1 = b1[n1] + b2[n1];
    }
    const int m0 = tm * 64 + wm + fq * 4;
#pragma unroll
    for (int r = 0; r < 4; ++r) {
        C[(size_t)(m0 + r) * 512 + n0]      = (acc00[r] + bias0) * TLOG2E;
        C[(size_t)(m0 + r) * 512 + n1]      = (acc01[r] + bias1) * TLOG2E;
        C[(size_t)(m0 + 16 + r) * 512 + n0] = (acc10[r] + bias0) * TLOG2E;
        C[(size_t)(m0 + 16 + r) * 512 + n1] = (acc11[r] + bias1) * TLOG2E;
    }
}

// ---------------------------------------------------------------------------
// Fused scores + softmax + context. Grid 256 = (tp << 3) | b (XCD pin),
// block = one t-PAIR, 1024 threads (16 waves -> 50% occupancy, fixes R7's
// 1-block/CU 8-wave cap).
//
// Phase 1: thread (half = tid>>9, s = tid&511) streams its k-row's d-HALF
//   from global (halves read disjoint 1 KB -> k-traffic stays 256 MB);
//   q0/delta/scale are LDS broadcasts. Exp-share across the t-pair:
//   e1 = e0*delta_d (1.5 trans/elem). Halves combine via one LDS exchange.
// Phase 2: waves 0-7 (tid<512) do the 2-row softmax (shfl + LDS combine);
//   barriers hoisted so all 16 waves participate.
// Phase 3: all 1024 threads: (g = tid>>7 s-group of 64, v4 = tid&127);
//   float4 value loads (value[b] read once per block = 256 MB total);
//   8-partial LDS combine.
// ---------------------------------------------------------------------------
__global__ __launch_bounds__(1024) void fused_attn(
    const float* __restrict__ qproj, const float* __restrict__ kproj,
    const int*   __restrict__ mask,  const float* __restrict__ scale,
    const float* __restrict__ value,
    float* __restrict__ ctx, float* __restrict__ attn)
{
    const int blk = blockIdx.x;
    const int b  = blk & 7;
    const int tp = blk >> 3;          // 0..31
    const size_t row0 = (size_t)(b * T_ + tp * 2);

    __shared__ __align__(16) float q0A[512];
    __shared__ __align__(16) float dA[512];
    __shared__ __align__(16) float cA[512];
    __shared__ __align__(16) float2 pex[512];      // high-half partials
    __shared__ __align__(16) float2 wp2[512];
    __shared__ __align__(16) float4 part[2][8][128];
    __shared__ float2 red2[16];

    const int tid  = threadIdx.x;     // 0..1023
    const int lane = tid & 63;
    const int wid  = tid >> 6;        // 0..15

    // ---- Phase 0: q0 / delta / scale into LDS (SoA) ----
    if (tid < 512) {
        float q0v = qproj[row0 * D_ + tid];
        float q1v = qproj[(row0 + 1) * D_ + tid];
        q0A[tid] = q0v;
        dA[tid]  = __builtin_amdgcn_exp2f(q1v - q0v);   // delta_d
        cA[tid]  = scale[tid];
    }
    __syncthreads();

    // ---- Phase 1: thread (half, s), d-range [half*256, half*256+256) ----
    const int s    = tid & 511;
    const int half = tid >> 9;
    const int dlo  = half << 8;
    const int m = mask[b * S_ + s];
    const float* kr = kproj + (size_t)(b * S_ + s) * D_ + dlo;
    float p0 = 0.f, p1 = 0.f;

    float4 kf0 = ((const float4*)kr)[0];
    float4 kf1 = ((const float4*)kr)[1];
    float4 kf2 = ((const float4*)kr)[2];
    float4 kf3 = ((const float4*)kr)[3];

#define SC_STEP(K4, DD) do {                                                  \
        float4 q4 = *(const float4*)&q0A[DD];                                 \
        float4 dl = *(const float4*)&dA[DD];                                  \
        float4 c4 = *(const float4*)&cA[DD];                                  \
        float e, ra, rb;                                                      \
        e  = __builtin_amdgcn_exp2f(q4.x + (K4).x);                           \
        ra = __builtin_amdgcn_rcpf(e + 1.0f);                                 \
        rb = __builtin_amdgcn_rcpf(fmaf(e, dl.x, 1.0f));                      \
        p0 = fmaf(c4.x, ra, p0); p1 = fmaf(c4.x, rb, p1);                     \
        e  = __builtin_amdgcn_exp2f(q4.y + (K4).y);                           \
        ra = __builtin_amdgcn_rcpf(e + 1.0f);                                 \
        rb = __builtin_amdgcn_rcpf(fmaf(e, dl.y, 1.0f));                      \
        p0 = fmaf(c4.y, ra, p0); p1 = fmaf(c4.y, rb, p1);                     \
        e  = __builtin_amdgcn_exp2f(q4.z + (K4).z);                           \
        ra = __builtin_amdgcn_rcpf(e + 1.0f);                                 \
        rb = __builtin_amdgcn_rcpf(fmaf(e, dl.z, 1.0f));                      \
        p0 = fmaf(c4.z, ra, p0); p1 = fmaf(c4.z, rb, p1);                     \
        e  = __builtin_amdgcn_exp2f(q4.w + (K4).w);                           \
        ra = __builtin_amdgcn_rcpf(e + 1.0f);                                 \
        rb = __builtin_amdgcn_rcpf(fmaf(e, dl.w, 1.0f));                      \
        p0 = fmaf(c4.w, ra, p0); p1 = fmaf(c4.w, rb, p1);                     \
    } while (0)

    for (int c = 0; c < 16; ++c) {
        const int nx = ((c + 1) & 15) * 16;   // wrap prefetch (last redundant)
        float4 nf0 = ((const float4*)(kr + nx))[0];
        float4 nf1 = ((const float4*)(kr + nx))[1];
        float4 nf2 = ((const float4*)(kr + nx))[2];
        float4 nf3 = ((const float4*)(kr + nx))[3];
        const int d0 = dlo + c * 16;
        SC_STEP(kf0, d0);
        SC_STEP(kf1, d0 + 4);
        SC_STEP(kf2, d0 + 8);
        SC_STEP(kf3, d0 + 12);
        kf0 = nf0; kf1 = nf1; kf2 = nf2; kf3 = nf3;
    }
#undef SC_STEP

    if (half == 1) { float2 pp; pp.x = p0; pp.y = p1; pex[s] = pp; }
    __syncthreads();

    // ---- Phase 2: softmax over 512 s (waves 0-7), barriers shared ----
    float x0 = 0.f, x1 = 0.f;
    if (tid < 512) {
        float2 ph = pex[s];
        p0 += ph.x; p1 += ph.y;
        x0 = m ? (-2.0f * p0) : -1e9f;
        x1 = m ? (-2.0f * p1) : -1e9f;
        float2 mx; mx.x = x0; mx.y = x1;
#pragma unroll
        for (int off = 32; off >= 1; off >>= 1) {
            mx.x = fmaxf(mx.x, __shfl_xor(mx.x, off));
            mx.y = fmaxf(mx.y, __shfl_xor(mx.y, off));
        }
        if (lane == 0) red2[wid] = mx;
    }
    __syncthreads();

    float e0 = 0.f, e1 = 0.f;
    if (tid < 512) {
        float2 M = red2[0];
#pragma unroll
        for (int i = 1; i < 8; ++i) {
            M.x = fmaxf(M.x, red2[i].x);
            M.y = fmaxf(M.y, red2[i].y);
        }
        e0 = __builtin_amdgcn_exp2f((x0 - M.x) * LOG2E);
        e1 = __builtin_amdgcn_exp2f((x1 - M.y) * LOG2E);
        float2 sm; sm.x = e0; sm.y = e1;
#pragma unroll
        for (int off = 32; off >= 1; off >>= 1) {
            sm.x += __shfl_xor(sm.x, off);
            sm.y += __shfl_xor(sm.y, off);
        }
        if (lane == 0) red2[8 + wid] = sm;
    }
    __syncthreads();

    if (tid < 512) {
        float2 SS = red2[8];
#pragma unroll
        for (int i = 9; i < 16; ++i) {
            SS.x += red2[i].x;
            SS.y += red2[i].y;
        }
        const float w0 = e0 * __builtin_amdgcn_rcpf(SS.x);
        const float w1 = e1 * __builtin_amdgcn_rcpf(SS.y);
        float2 wpair; wpair.x = w0; wpair.y = w1;
        wp2[s] = wpair;
        attn[row0 * S_ + s]       = w0;
        attn[(row0 + 1) * S_ + s] = w1;
    }
    __syncthreads();

    // ---- Phase 3: context, all 16 waves ----
    const int g  = tid >> 7;          // s-group 0..7 (64 s each)
    const int v4 = tid & 127;         // float4 slot
    const float* vb = value + ((size_t)(b * S_) + g * 64) * D_ + v4 * 4;
    float4 a0; a0.x = 0.f; a0.y = 0.f; a0.z = 0.f; a0.w = 0.f;
    float4 a1 = a0;
#pragma unroll 4
    for (int i = 0; i < 64; ++i) {
        float4 vv = *(const float4*)(vb + (size_t)i * D_);
        float2 w = wp2[g * 64 + i];
        a0.x = fmaf(w.x, vv.x, a0.x); a0.y = fmaf(w.x, vv.y, a0.y);
        a0.z = fmaf(w.x, vv.z, a0.z); a0.w = fmaf(w.x, vv.w, a0.w);
        a1.x = fmaf(w.y, vv.x, a1.x); a1.y = fmaf(w.y, vv.y, a1.y);
        a1.z = fmaf(w.y, vv.z, a1.z); a1.w = fmaf(w.y, vv.w, a1.w);
    }
    part[0][g][v4] = a0;
    part[1][g][v4] = a1;
    __syncthreads();
    if (tid < 256) {
        const int t = tid >> 7, v = tid & 127;
        float4 o; o.x = 0.f; o.y = 0.f; o.z = 0.f; o.w = 0.f;
#pragma unroll
        for (int gg = 0; gg < 8; ++gg) {
            float4 p = part[t][gg][v];
            o.x += p.x; o.y += p.y; o.z += p.z; o.w += p.w;
        }
        *(float4*)(ctx + (row0 + t) * D_ + v * 4) = o;
    }
}

extern "C" void kernel_launch(void* const* d_in, const int* in_sizes, int n_in,
                              void* d_out, int out_size, void* d_ws, size_t ws_size,
                              hipStream_t stream) {
    const float* query = (const float*)d_in[0];
    const float* value = (const float*)d_in[1];
    const int*   mask  = (const int*)  d_in[2];
    const float* W1w   = (const float*)d_in[3];
    const float* W1b   = (const float*)d_in[4];
    const float* W2w   = (const float*)d_in[5];
    const float* W2b   = (const float*)d_in[6];
    const float* scale = (const float*)d_in[7];

    float* ctx  = (float*)d_out;
    float* attn = (float*)d_out + (size_t)B_ * T_ * D_;

    float* qproj = (float*)d_ws;              // QN f32 (1 MB)
    float* kproj = qproj + (size_t)QN;        // KN f32 (8 MB)

    mfma_gemm<<<576, 256, 0, stream>>>(query, value, W1w, W2w, W1b, W2b,
                                       qproj, kproj);
    fused_attn<<<256, 1024, 0, stream>>>(qproj, kproj, mask, scale, value,
                                         ctx, attn);
}

// Round 9
// 126.501 us; speedup vs baseline: 1.0776x; 1.0574x over previous
//
#include <hip/hip_runtime.h>
#include <hip/hip_bf16.h>

// Dims fixed by setup_inputs(): b=8, t=64, s=512, qu=vu=d=512.
#define B_  8
#define T_  64
#define S_  512
#define D_  512

#define QN (512 * 512)      // qproj elements (B*T x D)
#define KN (4096 * 512)     // kT elements (B x D x S)

#define TLOG2E 2.8853900817779268f   // 2*log2(e)
#define LOG2E  1.4426950408889634f

typedef __attribute__((ext_vector_type(8))) short bf16x8;
typedef __attribute__((ext_vector_type(4))) float f32x4;

// RNE f32x2 -> packed bf16x2 via v_cvt_pk_bf16_f32.
__device__ __forceinline__ unsigned int pk2(float a, float b) {
    float2 f; f.x = a; f.y = b;
    __hip_bfloat162 h = __float22bfloat162_rn(f);
    return *(unsigned int*)&h;
}

// ---------------------------------------------------------------------------
// bf16 MFMA projection GEMM (R8 dbuf structure). k-branch epilogue now writes
// kT[b][d][s] (TRANSPOSED): acc regs hold 4 consecutive s at fixed d ->
// float4 stores. This makes the consumer's k-reads coalescible (R8's 47 us
// fused plateau = 64 lines per wave-load on row-major kproj).
//   blocks [0,512):   kT = (value @ W2)^T  (tm = (x&7)*8 + ((x>>3)&7), tn=x>>6)
//   blocks [512,576): qproj = query @ W1 row-major (r=x-512: tm=r>>3, tn=r&7)
// Epilogue: *TLOG2E; q-GEMM adds (b1+b2) first.
// ---------------------------------------------------------------------------
__global__ __launch_bounds__(256) void mfma_gemm(
    const float* __restrict__ query, const float* __restrict__ value,
    const float* __restrict__ W1, const float* __restrict__ W2,
    const float* __restrict__ b1, const float* __restrict__ b2,
    float* __restrict__ qproj, float* __restrict__ kT)
{
    __shared__ __align__(16) unsigned short Ab[2][64][40];
    __shared__ __align__(16) unsigned short Bs[2][64][40];

    const int x = blockIdx.x;
    const float *A, *W;
    float* C;
    int tm, tn;
    bool isq;
    if (x < 512) {
        tm = (x & 7) * 8 + ((x >> 3) & 7);
        tn = x >> 6;
        A = value; W = W2; C = kT; isq = false;
    } else {
        int r = x - 512;
        tm = r >> 3; tn = r & 7;
        A = query; W = W1; C = qproj; isq = true;
    }

    const int tid  = threadIdx.x;
    const int lane = tid & 63;
    const int wid  = tid >> 6;
    const int wm = (wid & 1) * 32, wn = (wid >> 1) * 32;
    const int fm = lane & 15, fq = lane >> 4;

    f32x4 acc00 = {0.f, 0.f, 0.f, 0.f};
    f32x4 acc01 = acc00, acc10 = acc00, acc11 = acc00;

    const int ar = tid >> 2;
    const int ac = (tid & 3) * 8;
    const float* Ag = A + (size_t)(tm * 64 + ar) * 512 + ac;
    const int c0 = (tid & 15) * 4;
    const int kp = (tid >> 4) * 2;
    const float* Wg = W + (size_t)kp * 512 + tn * 64 + c0;

    float4 av0, av1, wv0, wv1;

#define STAGE(BUF) do {                                                       \
        uint4 pa;                                                             \
        pa.x = pk2(av0.x, av0.y); pa.y = pk2(av0.z, av0.w);                   \
        pa.z = pk2(av1.x, av1.y); pa.w = pk2(av1.z, av1.w);                   \
        *(uint4*)&Ab[BUF][ar][ac] = pa;                                       \
        *(unsigned int*)&Bs[BUF][c0 + 0][kp] = pk2(wv0.x, wv1.x);             \
        *(unsigned int*)&Bs[BUF][c0 + 1][kp] = pk2(wv0.y, wv1.y);             \
        *(unsigned int*)&Bs[BUF][c0 + 2][kp] = pk2(wv0.z, wv1.z);             \
        *(unsigned int*)&Bs[BUF][c0 + 3][kp] = pk2(wv0.w, wv1.w);             \
    } while (0)

    av0 = *(const float4*)(Ag);
    av1 = *(const float4*)(Ag + 4);
    wv0 = *(const float4*)(Wg);
    wv1 = *(const float4*)(Wg + 512);
    STAGE(0);
    av0 = *(const float4*)(Ag + 32);
    av1 = *(const float4*)(Ag + 36);
    wv0 = *(const float4*)(Wg + 32 * 512);
    wv1 = *(const float4*)(Wg + 33 * 512);
    __syncthreads();

#pragma unroll
    for (int i = 0; i < 16; ++i) {
        const int cur = i & 1, nxt = cur ^ 1;
        bf16x8 a0  = *(const bf16x8*)&Ab[cur][wm + fm][fq * 8];
        bf16x8 a1  = *(const bf16x8*)&Ab[cur][wm + 16 + fm][fq * 8];
        bf16x8 b0  = *(const bf16x8*)&Bs[cur][wn + fm][fq * 8];
        bf16x8 b1v = *(const bf16x8*)&Bs[cur][wn + 16 + fm][fq * 8];
        if (i < 15) {
            STAGE(nxt);
            const int kn = ((i + 2) & 15) * 32;
            av0 = *(const float4*)(Ag + kn);
            av1 = *(const float4*)(Ag + kn + 4);
            wv0 = *(const float4*)(Wg + (size_t)kn * 512);
            wv1 = *(const float4*)(Wg + (size_t)kn * 512 + 512);
        }
        acc00 = __builtin_amdgcn_mfma_f32_16x16x32_bf16(a0, b0,  acc00, 0, 0, 0);
        acc01 = __builtin_amdgcn_mfma_f32_16x16x32_bf16(a0, b1v, acc01, 0, 0, 0);
        acc10 = __builtin_amdgcn_mfma_f32_16x16x32_bf16(a1, b0,  acc10, 0, 0, 0);
        acc11 = __builtin_amdgcn_mfma_f32_16x16x32_bf16(a1, b1v, acc11, 0, 0, 0);
        __syncthreads();
    }
#undef STAGE

    // C/D layout (m89-verified): col = lane&15, row = fq*4 + reg.
    const int n0 = tn * 64 + wn + fm;
    const int n1 = n0 + 16;
    const int m0 = tm * 64 + wm + fq * 4;
    if (isq) {
        float bias0 = b1[n0] + b2[n0];
        float bias1 = b1[n1] + b2[n1];
#pragma unroll
        for (int r = 0; r < 4; ++r) {
            C[(size_t)(m0 + r) * 512 + n0]      = (acc00[r] + bias0) * TLOG2E;
            C[(size_t)(m0 + r) * 512 + n1]      = (acc01[r] + bias1) * TLOG2E;
            C[(size_t)(m0 + 16 + r) * 512 + n0] = (acc10[r] + bias0) * TLOG2E;
            C[(size_t)(m0 + 16 + r) * 512 + n1] = (acc11[r] + bias1) * TLOG2E;
        }
    } else {
        // kT[(bb*512 + d)*512 + s]; acc regs = 4 consecutive s at fixed d.
        const int bb = m0 >> 9;
        const int sl = m0 & 511;
        float* kb = C + (size_t)(bb * 512) * 512;
        float4 o;
        o.x = acc00[0] * TLOG2E; o.y = acc00[1] * TLOG2E;
        o.z = acc00[2] * TLOG2E; o.w = acc00[3] * TLOG2E;
        *(float4*)(kb + (size_t)n0 * 512 + sl) = o;
        o.x = acc10[0] * TLOG2E; o.y = acc10[1] * TLOG2E;
        o.z = acc10[2] * TLOG2E; o.w = acc10[3] * TLOG2E;
        *(float4*)(kb + (size_t)n0 * 512 + sl + 16) = o;
        o.x = acc01[0] * TLOG2E; o.y = acc01[1] * TLOG2E;
        o.z = acc01[2] * TLOG2E; o.w = acc01[3] * TLOG2E;
        *(float4*)(kb + (size_t)n1 * 512 + sl) = o;
        o.x = acc11[0] * TLOG2E; o.y = acc11[1] * TLOG2E;
        o.z = acc11[2] * TLOG2E; o.w = acc11[3] * TLOG2E;
        *(float4*)(kb + (size_t)n1 * 512 + sl + 16) = o;
    }
}

// ---------------------------------------------------------------------------
// Fused scores + softmax + context. Grid 256 = (tp << 3) | b (XCD pin),
// block = one t-PAIR, 1024 threads.
//
// Phase 1 (COALESCED, fixes R7/R8's 64-lines-per-load): thread = (s-pair
//   sp=tid&255, d-quarter dq=tid>>8). Loads float2 of kT[b][d][s] (both s of
//   the pair at depth d): wave = 256 consecutive s -> 8 lines/instr.
//   q0/delta/scale via LDS b128 broadcasts. Exp-share: e1 = e0*delta_d.
//   4 d-quarter partials combined through pex[4][256] (float4 per s-pair).
// Phase 2: waves 0-7 softmax (barriers hoisted block-wide).
// Phase 3: all 16 waves, coalesced float4 value loads, 8-partial combine.
// ---------------------------------------------------------------------------
__global__ __launch_bounds__(1024) void fused_attn(
    const float* __restrict__ qproj, const float* __restrict__ kT,
    const int*   __restrict__ mask,  const float* __restrict__ scale,
    const float* __restrict__ value,
    float* __restrict__ ctx, float* __restrict__ attn)
{
    const int blk = blockIdx.x;
    const int b  = blk & 7;
    const int tp = blk >> 3;          // 0..31
    const size_t row0 = (size_t)(b * T_ + tp * 2);

    __shared__ __align__(16) float q0A[512];
    __shared__ __align__(16) float dA[512];
    __shared__ __align__(16) float cA[512];
    __shared__ __align__(16) float4 pex[4][256];   // (t0s0,t1s0,t0s1,t1s1)
    __shared__ __align__(16) float2 wp2[512];
    __shared__ __align__(16) float4 part[2][8][128];
    __shared__ float2 red2[16];

    const int tid  = threadIdx.x;     // 0..1023
    const int lane = tid & 63;
    const int wid  = tid >> 6;        // 0..15

    // ---- Phase 0: q0 / delta / scale into LDS ----
    if (tid < 512) {
        float q0v = qproj[row0 * D_ + tid];
        float q1v = qproj[(row0 + 1) * D_ + tid];
        q0A[tid] = q0v;
        dA[tid]  = __builtin_amdgcn_exp2f(q1v - q0v);   // delta_d
        cA[tid]  = scale[tid];
    }
    __syncthreads();

    // ---- Phase 1: thread (sp, dq) ----
    const int sp  = tid & 255;        // s-pair
    const int dq  = tid >> 8;         // d-quarter
    const int dlo = dq * 128;
    const float* kb = kT + ((size_t)(b * 512 + dlo)) * 512 + sp * 2;

    float p00 = 0.f, p10 = 0.f, p01 = 0.f, p11 = 0.f;

    float2 nf0 = *(const float2*)(kb);
    float2 nf1 = *(const float2*)(kb + 512);
    float2 nf2 = *(const float2*)(kb + 1024);
    float2 nf3 = *(const float2*)(kb + 1536);

#define SC2(KF, QV, DV, CV) do {                                              \
        float e0 = __builtin_amdgcn_exp2f((QV) + (KF).x);                     \
        float ra = __builtin_amdgcn_rcpf(e0 + 1.0f);                          \
        float rb = __builtin_amdgcn_rcpf(fmaf(e0, (DV), 1.0f));               \
        p00 = fmaf((CV), ra, p00); p10 = fmaf((CV), rb, p10);                 \
        float e1 = __builtin_amdgcn_exp2f((QV) + (KF).y);                     \
        float rc = __builtin_amdgcn_rcpf(e1 + 1.0f);                          \
        float rd = __builtin_amdgcn_rcpf(fmaf(e1, (DV), 1.0f));               \
        p01 = fmaf((CV), rc, p01); p11 = fmaf((CV), rd, p11);                 \
    } while (0)

    for (int g = 0; g < 32; ++g) {
        float2 kf0 = nf0, kf1 = nf1, kf2 = nf2, kf3 = nf3;
        const float* nb = kb + (size_t)(((g + 1) & 31) * 4) * 512;  // wrap
        nf0 = *(const float2*)(nb);
        nf1 = *(const float2*)(nb + 512);
        nf2 = *(const float2*)(nb + 1024);
        nf3 = *(const float2*)(nb + 1536);
        const int d0 = dlo + g * 4;
        float4 q4 = *(const float4*)&q0A[d0];
        float4 dl = *(const float4*)&dA[d0];
        float4 c4 = *(const float4*)&cA[d0];
        SC2(kf0, q4.x, dl.x, c4.x);
        SC2(kf1, q4.y, dl.y, c4.y);
        SC2(kf2, q4.z, dl.z, c4.z);
        SC2(kf3, q4.w, dl.w, c4.w);
    }
#undef SC2

    {
        float4 pq; pq.x = p00; pq.y = p10; pq.z = p01; pq.w = p11;
        pex[dq][sp] = pq;
    }
    __syncthreads();

    // ---- Phase 2: softmax over 512 s (waves 0-7), barriers block-wide ----
    float x0 = 0.f, x1 = 0.f;
    if (tid < 512) {
        const int s = tid;
        const int s2 = s >> 1;
        const bool odd = (s & 1) != 0;
        float4 r0 = pex[0][s2], r1 = pex[1][s2];
        float4 r2 = pex[2][s2], r3 = pex[3][s2];
        float pt0 = odd ? ((r0.z + r1.z) + (r2.z + r3.z))
                        : ((r0.x + r1.x) + (r2.x + r3.x));
        float pt1 = odd ? ((r0.w + r1.w) + (r2.w + r3.w))
                        : ((r0.y + r1.y) + (r2.y + r3.y));
        const int m = mask[b * S_ + s];
        x0 = m ? (-2.0f * pt0) : -1e9f;
        x1 = m ? (-2.0f * pt1) : -1e9f;
        float2 mx; mx.x = x0; mx.y = x1;
#pragma unroll
        for (int off = 32; off >= 1; off >>= 1) {
            mx.x = fmaxf(mx.x, __shfl_xor(mx.x, off));
            mx.y = fmaxf(mx.y, __shfl_xor(mx.y, off));
        }
        if (lane == 0) red2[wid] = mx;
    }
    __syncthreads();

    float e0 = 0.f, e1 = 0.f;
    if (tid < 512) {
        float2 M = red2[0];
#pragma unroll
        for (int i = 1; i < 8; ++i) {
            M.x = fmaxf(M.x, red2[i].x);
            M.y = fmaxf(M.y, red2[i].y);
        }
        e0 = __builtin_amdgcn_exp2f((x0 - M.x) * LOG2E);
        e1 = __builtin_amdgcn_exp2f((x1 - M.y) * LOG2E);
        float2 sm; sm.x = e0; sm.y = e1;
#pragma unroll
        for (int off = 32; off >= 1; off >>= 1) {
            sm.x += __shfl_xor(sm.x, off);
            sm.y += __shfl_xor(sm.y, off);
        }
        if (lane == 0) red2[8 + wid] = sm;
    }
    __syncthreads();

    if (tid < 512) {
        const int s = tid;
        float2 SS = red2[8];
#pragma unroll
        for (int i = 9; i < 16; ++i) {
            SS.x += red2[i].x;
            SS.y += red2[i].y;
        }
        const float w0 = e0 * __builtin_amdgcn_rcpf(SS.x);
        const float w1 = e1 * __builtin_amdgcn_rcpf(SS.y);
        float2 wpair; wpair.x = w0; wpair.y = w1;
        wp2[s] = wpair;
        attn[row0 * S_ + s]       = w0;
        attn[(row0 + 1) * S_ + s] = w1;
    }
    __syncthreads();

    // ---- Phase 3: context, all 16 waves ----
    const int g  = tid >> 7;          // s-group 0..7 (64 s each)
    const int v4 = tid & 127;
    const float* vb = value + ((size_t)(b * S_) + g * 64) * D_ + v4 * 4;
    float4 a0; a0.x = 0.f; a0.y = 0.f; a0.z = 0.f; a0.w = 0.f;
    float4 a1 = a0;
#pragma unroll 4
    for (int i = 0; i < 64; ++i) {
        float4 vv = *(const float4*)(vb + (size_t)i * D_);
        float2 w = wp2[g * 64 + i];
        a0.x = fmaf(w.x, vv.x, a0.x); a0.y = fmaf(w.x, vv.y, a0.y);
        a0.z = fmaf(w.x, vv.z, a0.z); a0.w = fmaf(w.x, vv.w, a0.w);
        a1.x = fmaf(w.y, vv.x, a1.x); a1.y = fmaf(w.y, vv.y, a1.y);
        a1.z = fmaf(w.y, vv.z, a1.z); a1.w = fmaf(w.y, vv.w, a1.w);
    }
    part[0][g][v4] = a0;
    part[1][g][v4] = a1;
    __syncthreads();
    if (tid < 256) {
        const int t = tid >> 7, v = tid & 127;
        float4 o; o.x = 0.f; o.y = 0.f; o.z = 0.f; o.w = 0.f;
#pragma unroll
        for (int gg = 0; gg < 8; ++gg) {
            float4 p = part[t][gg][v];
            o.x += p.x; o.y += p.y; o.z += p.z; o.w += p.w;
        }
        *(float4*)(ctx + (row0 + t) * D_ + v * 4) = o;
    }
}

extern "C" void kernel_launch(void* const* d_in, const int* in_sizes, int n_in,
                              void* d_out, int out_size, void* d_ws, size_t ws_size,
                              hipStream_t stream) {
    const float* query = (const float*)d_in[0];
    const float* value = (const float*)d_in[1];
    const int*   mask  = (const int*)  d_in[2];
    const float* W1w   = (const float*)d_in[3];
    const float* W1b   = (const float*)d_in[4];
    const float* W2w   = (const float*)d_in[5];
    const float* W2b   = (const float*)d_in[6];
    const float* scale = (const float*)d_in[7];

    float* ctx  = (float*)d_out;
    float* attn = (float*)d_out + (size_t)B_ * T_ * D_;

    float* qproj = (float*)d_ws;              // QN f32 (1 MB)
    float* kT    = qproj + (size_t)QN;        // KN f32 (8 MB), [b][d][s]

    mfma_gemm<<<576, 256, 0, stream>>>(query, value, W1w, W2w, W1b, W2b,
                                       qproj, kT);
    fused_attn<<<256, 1024, 0, stream>>>(qproj, kT, mask, scale, value,
                                         ctx, attn);
}